// Round 1
// baseline (887.584 us; speedup 1.0000x reference)
//
#include <hip/hip_runtime.h>
#include <cstddef>

#define BSZ  2
#define SEQ  4096
#define HQN  32
#define HKVN 2
#define DIM  128
#define NBK  255
#define GRP  16

// ============================ compression ============================
// kc[b,n,h,do] = sum_{t,din} (x[b, n*16+t, h, din] + pe[t,din]) * w[t*128+din, do]
// grid 512 = bh(4) x tile(64) x kv(2), block 256. NT=4 blocks per tile.
__global__ __launch_bounds__(256) void compress_kernel(
    const float* __restrict__ kin, const float* __restrict__ vin,
    const float* __restrict__ wk,  const float* __restrict__ wv,
    const float* __restrict__ pek, const float* __restrict__ pev,
    float* __restrict__ kc, float* __restrict__ vc)
{
  __shared__ float xL[80 * 128];     // 40 KB: 80 staged x rows
  __shared__ float peL[4096];        // 16 KB
  __shared__ float red[3 * 32 * 20]; // 7.5 KB cross-wave reduction

  const int tid  = threadIdx.x;
  const int bid  = blockIdx.x;
  const int kv   = bid & 1;
  const int tile = (bid >> 1) & 63;
  const int bh   = bid >> 7;
  const int b = bh >> 1, h = bh & 1;

  const float* x  = kv ? vin : kin;
  const float* w  = kv ? wv  : wk;
  const float* pe = kv ? pev : pek;
  float* outc     = kv ? vc  : kc;

  const float4* x4  = (const float4*)x;
  const float4* w4  = (const float4*)w;
  const float4* pe4 = (const float4*)pe;

  // stage 80 rows of x (rows tile*64 .. tile*64+79), clamped
  #pragma unroll
  for (int i = 0; i < 10; ++i) {
    const int f = tid + (i << 8);         // 0..2559
    const int r = f >> 5, d4 = f & 31;
    long gr = (long)b * SEQ + tile * 64 + r;
    if (gr > (long)BSZ * SEQ - 1) gr = (long)BSZ * SEQ - 1;
    const float4 val = x4[(gr * HKVN + h) * 32 + d4];
    *(float4*)&xL[r * 128 + d4 * 4] = val;
  }
  #pragma unroll
  for (int i = 0; i < 4; ++i) {
    const int f = tid + (i << 8);
    *(float4*)&peL[f * 4] = pe4[f];
  }
  __syncthreads();

  const int dg = tid & 31, part = tid >> 5;   // do-group, e-slice
  float4 a0 = {0,0,0,0}, a1 = {0,0,0,0}, a2 = {0,0,0,0}, a3 = {0,0,0,0}, ab = {0,0,0,0};
  const int e0 = part * 512;
  #pragma unroll 4
  for (int it = 0; it < 512; ++it) {
    const int e = e0 + it;
    const float4 wv4 = w4[e * 32 + dg];
    const float pv = peL[e];
    const float x0 = xL[e], x1 = xL[2048 + e], x2 = xL[4096 + e], x3 = xL[6144 + e];
    ab.x += pv * wv4.x; ab.y += pv * wv4.y; ab.z += pv * wv4.z; ab.w += pv * wv4.w;
    a0.x += x0 * wv4.x; a0.y += x0 * wv4.y; a0.z += x0 * wv4.z; a0.w += x0 * wv4.w;
    a1.x += x1 * wv4.x; a1.y += x1 * wv4.y; a1.z += x1 * wv4.z; a1.w += x1 * wv4.w;
    a2.x += x2 * wv4.x; a2.y += x2 * wv4.y; a2.z += x2 * wv4.z; a2.w += x2 * wv4.w;
    a3.x += x3 * wv4.x; a3.y += x3 * wv4.y; a3.z += x3 * wv4.z; a3.w += x3 * wv4.w;
  }
  // pair-reduce e-slices (part, part^1) via xor-32 shuffle within wave
  a0.x += __shfl_xor(a0.x, 32); a0.y += __shfl_xor(a0.y, 32); a0.z += __shfl_xor(a0.z, 32); a0.w += __shfl_xor(a0.w, 32);
  a1.x += __shfl_xor(a1.x, 32); a1.y += __shfl_xor(a1.y, 32); a1.z += __shfl_xor(a1.z, 32); a1.w += __shfl_xor(a1.w, 32);
  a2.x += __shfl_xor(a2.x, 32); a2.y += __shfl_xor(a2.y, 32); a2.z += __shfl_xor(a2.z, 32); a2.w += __shfl_xor(a2.w, 32);
  a3.x += __shfl_xor(a3.x, 32); a3.y += __shfl_xor(a3.y, 32); a3.z += __shfl_xor(a3.z, 32); a3.w += __shfl_xor(a3.w, 32);
  ab.x += __shfl_xor(ab.x, 32); ab.y += __shfl_xor(ab.y, 32); ab.z += __shfl_xor(ab.z, 32); ab.w += __shfl_xor(ab.w, 32);

  const int wv_ = tid >> 6, inw = tid & 63;
  if (wv_ > 0 && inw < 32) {
    float* rp = &red[((wv_ - 1) * 32 + dg) * 20];
    rp[0] = a0.x; rp[1] = a0.y; rp[2] = a0.z; rp[3] = a0.w;
    rp[4] = a1.x; rp[5] = a1.y; rp[6] = a1.z; rp[7] = a1.w;
    rp[8] = a2.x; rp[9] = a2.y; rp[10] = a2.z; rp[11] = a2.w;
    rp[12] = a3.x; rp[13] = a3.y; rp[14] = a3.z; rp[15] = a3.w;
    rp[16] = ab.x; rp[17] = ab.y; rp[18] = ab.z; rp[19] = ab.w;
  }
  __syncthreads();
  if (tid < 32) {
    #pragma unroll
    for (int wvv = 0; wvv < 3; ++wvv) {
      const float* rp = &red[(wvv * 32 + tid) * 20];
      a0.x += rp[0]; a0.y += rp[1]; a0.z += rp[2]; a0.w += rp[3];
      a1.x += rp[4]; a1.y += rp[5]; a1.z += rp[6]; a1.w += rp[7];
      a2.x += rp[8]; a2.y += rp[9]; a2.z += rp[10]; a2.w += rp[11];
      a3.x += rp[12]; a3.y += rp[13]; a3.z += rp[14]; a3.w += rp[15];
      ab.x += rp[16]; ab.y += rp[17]; ab.z += rp[18]; ab.w += rp[19];
    }
    const int n0 = tile * 4;
    float4 o;
    if (n0 + 0 < NBK) { o.x = a0.x + ab.x; o.y = a0.y + ab.y; o.z = a0.z + ab.z; o.w = a0.w + ab.w;
      *(float4*)&outc[((size_t)((b * HKVN + h) * NBK + n0 + 0)) * DIM + tid * 4] = o; }
    if (n0 + 1 < NBK) { o.x = a1.x + ab.x; o.y = a1.y + ab.y; o.z = a1.z + ab.z; o.w = a1.w + ab.w;
      *(float4*)&outc[((size_t)((b * HKVN + h) * NBK + n0 + 1)) * DIM + tid * 4] = o; }
    if (n0 + 2 < NBK) { o.x = a2.x + ab.x; o.y = a2.y + ab.y; o.z = a2.z + ab.z; o.w = a2.w + ab.w;
      *(float4*)&outc[((size_t)((b * HKVN + h) * NBK + n0 + 2)) * DIM + tid * 4] = o; }
    if (n0 + 3 < NBK) { o.x = a3.x + ab.x; o.y = a3.y + ab.y; o.z = a3.z + ab.z; o.w = a3.w + ab.w;
      *(float4*)&outc[((size_t)((b * HKVN + h) * NBK + n0 + 3)) * DIM + tid * 4] = o; }
  }
}

// ============================ fused attention ============================
// grid 4096 = bh(4) x stile(1024), block 256.
// 64 rows = 4 queries x 16 gqa-heads; thread tile 4 rows x 16 cols of the
// 64x255 score matrix; full-row softmax via 16-lane shuffles; P -> LDS ->
// coalesced attn_prob stores + PV GEMM.

#define G1FMA(CC) do { \
  const float4 kvv = *(const float4*)&smC[dd * 256 + (((((CC) << 4) | cg) ^ swk) << 2)]; \
  sc[0][(CC)*4+0] += qv.x*kvv.x; sc[0][(CC)*4+1] += qv.x*kvv.y; sc[0][(CC)*4+2] += qv.x*kvv.z; sc[0][(CC)*4+3] += qv.x*kvv.w; \
  sc[1][(CC)*4+0] += qv.y*kvv.x; sc[1][(CC)*4+1] += qv.y*kvv.y; sc[1][(CC)*4+2] += qv.y*kvv.z; sc[1][(CC)*4+3] += qv.y*kvv.w; \
  sc[2][(CC)*4+0] += qv.z*kvv.x; sc[2][(CC)*4+1] += qv.z*kvv.y; sc[2][(CC)*4+2] += qv.z*kvv.z; sc[2][(CC)*4+3] += qv.z*kvv.w; \
  sc[3][(CC)*4+0] += qv.w*kvv.x; sc[3][(CC)*4+1] += qv.w*kvv.y; sc[3][(CC)*4+2] += qv.w*kvv.z; sc[3][(CC)*4+3] += qv.w*kvv.w; \
} while (0)

#define G2FMA(RI, PR) do { \
  oa[RI][0].x += (PR)*v0.x; oa[RI][0].y += (PR)*v0.y; oa[RI][0].z += (PR)*v0.z; oa[RI][0].w += (PR)*v0.w; \
  oa[RI][1].x += (PR)*v1.x; oa[RI][1].y += (PR)*v1.y; oa[RI][1].z += (PR)*v1.z; oa[RI][1].w += (PR)*v1.w; \
} while (0)

__global__ __launch_bounds__(256, 2) void attn_kernel(
    const float* __restrict__ q, const float* __restrict__ kcg,
    const float* __restrict__ vcg, float* __restrict__ outp,
    float* __restrict__ ap)
{
  __shared__ float smQ[128 * 64];  // 32 KB: qT (swizzled); later pT (stride 68)
  __shared__ float smC[32 * 256];  // 32 KB: kcT d-chunks (swizzled); later vc chunk [64][128]

  const int tid = threadIdx.x;
  const int bid = blockIdx.x;
  const int stile = bid & 1023;
  const int bh = bid >> 10;
  const int b = bh >> 1, h = bh & 1;
  const int s0 = stile << 2;

  const int cg = tid & 15, rg = tid >> 4;
  const int s = s0 + (rg >> 2);            // this thread's query position
  const int gbase = (rg & 3) << 2;         // g = gbase + ri

  const int nvis = (s >= 31) ? (((s - 31) >> 4) + 1) : 0;
  const int smax = s0 + 3;
  const int nvis_max = (smax >= 31) ? (((smax - 31) >> 4) + 1) : 0;
  const int nchunks = (nvis_max + 63) >> 6;  // active 64-col chunks, 0..4

  // ---- stage Q transposed + swizzled: qT[d][r], group (r>>2)^( (d>>2)&15 ) ----
  {
    const float4* q4 = (const float4*)q;
    #pragma unroll
    for (int i = 0; i < 8; ++i) {
      const int f = tid + (i << 8);     // 0..2047
      const int r = f >> 5, d4 = f & 31;
      const size_t grow = (size_t)(b * SEQ + s0 + (r >> 4)) * HQN + h * GRP + (r & 15);
      const float4 val = q4[grow * 32 + d4];
      float* dst = &smQ[d4 * 256 + ((((r >> 2) ^ (d4 & 15)) << 2) | (r & 3))];
      dst[0] = val.x; dst[64] = val.y; dst[128] = val.z; dst[192] = val.w;
    }
  }
  __syncthreads();

  float sc[4][16];
  #pragma unroll
  for (int a = 0; a < 4; ++a)
    #pragma unroll
    for (int c = 0; c < 16; ++c) sc[a][c] = 0.f;

  const float4* kc4 = (const float4*)(kcg + (size_t)(b * HKVN + h) * NBK * DIM);
  const float4* vc4 = (const float4*)(vcg + (size_t)(b * HKVN + h) * NBK * DIM);

  // ---- GEMM1: scores = Q @ kc^T, K-dim (d=128) chunked by 32 ----
  if (nchunks > 0) {
    for (int kc32 = 0; kc32 < 4; ++kc32) {
      #pragma unroll
      for (int i = 0; i < 8; ++i) {
        const int f = tid + (i << 8);       // 0..2047
        const int c = f >> 3;               // col 0..255
        const int d8 = f & 7;               // float4 along d within 32
        int n = c; if (n > NBK - 1) n = NBK - 1;
        const float4 val = kc4[(size_t)n * 32 + kc32 * 8 + d8];
        const int cq = c >> 2, cr = c & 3;
        const int dd0 = d8 * 4;
        smC[(dd0 + 0) * 256 + (((cq ^ ((dd0 + 0) & 15)) << 2) | cr)] = val.x;
        smC[(dd0 + 1) * 256 + (((cq ^ ((dd0 + 1) & 15)) << 2) | cr)] = val.y;
        smC[(dd0 + 2) * 256 + (((cq ^ ((dd0 + 2) & 15)) << 2) | cr)] = val.z;
        smC[(dd0 + 3) * 256 + (((cq ^ ((dd0 + 3) & 15)) << 2) | cr)] = val.w;
      }
      __syncthreads();
      #pragma unroll 4
      for (int dd = 0; dd < 32; ++dd) {
        const int d = (kc32 << 5) + dd;
        const int swq = (d >> 2) & 15;
        const float4 qv = *(const float4*)&smQ[d * 64 + ((rg ^ swq) << 2)];
        const int swk = dd & 15;
        if (0 < nchunks) G1FMA(0);
        if (1 < nchunks) G1FMA(1);
        if (2 < nchunks) G1FMA(2);
        if (3 < nchunks) G1FMA(3);
      }
      __syncthreads();
    }
  }

  // ---- softmax (scale, causal mask, row max/sum via 16-lane xor shuffles) ----
  const float scale = 0.08838834764831845f;  // 1/sqrt(128)
  #pragma unroll
  for (int ri = 0; ri < 4; ++ri) {
    float mv = -3.0e38f;
    #pragma unroll
    for (int j = 0; j < 16; ++j) {
      const float sv = sc[ri][j] * scale;
      sc[ri][j] = sv;
      const int cglob = ((j >> 2) << 6) + (cg << 2) + (j & 3);
      if (cglob < nvis) mv = fmaxf(mv, sv);
    }
    mv = fmaxf(mv, __shfl_xor(mv, 1));
    mv = fmaxf(mv, __shfl_xor(mv, 2));
    mv = fmaxf(mv, __shfl_xor(mv, 4));
    mv = fmaxf(mv, __shfl_xor(mv, 8));
    float l = 0.f;
    #pragma unroll
    for (int j = 0; j < 16; ++j) {
      const int cglob = ((j >> 2) << 6) + (cg << 2) + (j & 3);
      const float e = (cglob < nvis) ? __expf(sc[ri][j] - mv) : 0.f;
      sc[ri][j] = e;
      l += e;
    }
    l += __shfl_xor(l, 1); l += __shfl_xor(l, 2);
    l += __shfl_xor(l, 4); l += __shfl_xor(l, 8);
    const float inv = 1.f / fmaxf(l, 1e-20f);
    #pragma unroll
    for (int j = 0; j < 16; ++j) sc[ri][j] *= inv;
  }

  // ---- GEMM2: out = P @ vc, per 64-col chunk; attn_prob stores from pT ----
  float4 oa[4][2];
  #pragma unroll
  for (int ri = 0; ri < 4; ++ri) { oa[ri][0] = {0,0,0,0}; oa[ri][1] = {0,0,0,0}; }

  const int wv_ = tid >> 6, ln = tid & 63;

  #pragma unroll
  for (int cc = 0; cc < 4; ++cc) {
    if (cc < nchunks) {
      // pT[c][r] (stride 68) in smQ
      #pragma unroll
      for (int ci = 0; ci < 4; ++ci) {
        float* pd = &smQ[((cg << 2) | ci) * 68 + (rg << 2)];
        pd[0] = sc[0][cc * 4 + ci]; pd[1] = sc[1][cc * 4 + ci];
        pd[2] = sc[2][cc * 4 + ci]; pd[3] = sc[3][cc * 4 + ci];
      }
      // vc chunk [64][128] in smC
      #pragma unroll
      for (int i = 0; i < 8; ++i) {
        const int f = tid + (i << 8);
        const int c = f >> 5, d4 = f & 31;
        int n = (cc << 6) + c; if (n > NBK - 1) n = NBK - 1;
        *(float4*)&smC[c * 128 + d4 * 4] = vc4[(size_t)n * 32 + d4];
      }
      __syncthreads();
      // coalesced attn_prob stores for this chunk (includes causal zeros)
      #pragma unroll
      for (int kk = 0; kk < 16; ++kk) {
        const int r = (wv_ << 4) + kk;
        const int c = (cc << 6) + ln;
        if (c < NBK) {
          const size_t ro = ((size_t)(b * HQN + h * GRP + (r & 15)) * SEQ + (s0 + (r >> 4))) * NBK;
          ap[ro + c] = smQ[ln * 68 + r];
        }
      }
      // PV accumulate
      const int cmax = min(64, nvis_max - (cc << 6));
      #pragma unroll 4
      for (int c = 0; c < cmax; ++c) {
        const float4 pv = *(const float4*)&smQ[c * 68 + (rg << 2)];
        const float4 v0 = *(const float4*)&smC[c * 128 + (cg << 2)];
        const float4 v1 = *(const float4*)&smC[c * 128 + 64 + (cg << 2)];
        G2FMA(0, pv.x); G2FMA(1, pv.y); G2FMA(2, pv.z); G2FMA(3, pv.w);
      }
      __syncthreads();
    }
  }

  // zero-fill attn_prob for fully-masked chunks
  for (int cc = nchunks; cc < 4; ++cc) {
    #pragma unroll
    for (int kk = 0; kk < 16; ++kk) {
      const int r = (wv_ << 4) + kk;
      const int c = (cc << 6) + ln;
      if (c < NBK) {
        const size_t ro = ((size_t)(b * HQN + h * GRP + (r & 15)) * SEQ + (s0 + (r >> 4))) * NBK;
        ap[ro + c] = 0.f;
      }
    }
  }

  // out stores (zeros when nothing visible)
  #pragma unroll
  for (int ri = 0; ri < 4; ++ri) {
    const size_t ob = ((size_t)(b * SEQ + s) * HQN + h * GRP + gbase + ri) * DIM;
    *(float4*)&outp[ob + (cg << 2)] = oa[ri][0];
    *(float4*)&outp[ob + 64 + (cg << 2)] = oa[ri][1];
  }
}

extern "C" void kernel_launch(void* const* d_in, const int* in_sizes, int n_in,
                              void* d_out, int out_size, void* d_ws, size_t ws_size,
                              hipStream_t stream)
{
  const float* q   = (const float*)d_in[0];
  const float* k   = (const float*)d_in[1];
  const float* v   = (const float*)d_in[2];
  // d_in[3] cu_seqlens_k: fixed [0,S,2S] layout already implied by indexing
  const float* wk  = (const float*)d_in[4];
  const float* wv  = (const float*)d_in[5];
  const float* pek = (const float*)d_in[6];
  const float* pev = (const float*)d_in[7];
  // d_in[8] causal == True (hardcoded), d_in[9] softmax_scale == 1/sqrt(128) (hardcoded)

  float* outp = (float*)d_out;
  float* ap   = outp + (size_t)BSZ * SEQ * HQN * DIM;  // attn_prob section

  float* kc = (float*)d_ws;                             // [b][hkv][255][128]
  float* vc = kc + (size_t)BSZ * HKVN * NBK * DIM;

  compress_kernel<<<dim3(512), dim3(256), 0, stream>>>(k, v, wk, wv, pek, pev, kc, vc);
  attn_kernel<<<dim3(4096), dim3(256), 0, stream>>>(q, kc, vc, outp, ap);
}